// Round 1
// baseline (951.953 us; speedup 1.0000x reference)
//
#include <hip/hip_runtime.h>
#include <math.h>

// Shapes (hardcoded from reference): B=8,T=12,N=1000,D=256,H=8,R=32,HD=32,E=1024
#define MT 96000   // B*T*N tokens
#define DD 256
#define EE 1024
#define NBT 96     // B*T
#define NSEQ 1000

typedef __attribute__((ext_vector_type(8))) short bf16x8;
typedef __attribute__((ext_vector_type(4))) short bf16x4;
typedef __attribute__((ext_vector_type(4))) float f32x4;

__device__ __forceinline__ short f2b(float f) {
  union { float f; unsigned u; } v; v.f = f;
  unsigned r = (v.u + 0x7FFFu + ((v.u >> 16) & 1u)) >> 16;
  return (short)r;
}
__device__ __forceinline__ float b2f(short s) {
  union { unsigned u; float f; } v; v.u = ((unsigned)(unsigned short)s) << 16;
  return v.f;
}
__device__ __forceinline__ float sigf(float x) { return 1.f / (1.f + __expf(-x)); }
__device__ __forceinline__ f32x4 mfma16(bf16x8 a, bf16x8 b, f32x4 c) {
  return __builtin_amdgcn_mfma_f32_16x16x32_bf16(a, b, c, 0, 0, 0);
}

// ---------------------------------------------------------------------------
// K0: weight prep. Transposed bf16 weights ([out][in] so B-fragments are 16B
// contiguous k-octets), plus fused Wqk = (Wq . key)/sqrt(HD) and bqk.
// ---------------------------------------------------------------------------
__global__ __launch_bounds__(256) void k_prep(
    const float* __restrict__ Wq, const float* __restrict__ bq,
    const float* __restrict__ key, const float* __restrict__ Wv,
    const float* __restrict__ W1, const float* __restrict__ W2,
    const float* __restrict__ W3,
    short* __restrict__ W1t, short* __restrict__ W2t, short* __restrict__ W3t,
    short* __restrict__ Wvt, short* __restrict__ Wqkt, float* __restrict__ bqk)
{
  int i = blockIdx.x * 256 + threadIdx.x;   // 0 .. 262143
  { int e = i >> 8, c = i & 255;            // W1t/W2t: [e][c]
    W1t[i] = f2b(W1[c * EE + e]);
    W2t[i] = f2b(W2[c * EE + e]); }
  { int n = i >> 10, e = i & 1023;          // W3t: [n][e]
    W3t[i] = f2b(W3[e * DD + n]); }
  if (i < 65536) {
    int n = i >> 8, c = i & 255;
    Wvt[i] = f2b(Wv[c * DD + n]);           // Wvt: [n][c]
    int h = n >> 5, r = n & 31;
    float acc = 0.f;
    for (int d = 0; d < 32; ++d)
      acc += Wq[c * DD + h * 32 + d] * key[(r * 8 + h) * 32 + d];
    Wqkt[i] = f2b(acc * 0.17677669529663687f);  // 1/sqrt(32)
  }
  if (i < 256) {
    int h = i >> 5, r = i & 31;
    float acc = 0.f;
    for (int d = 0; d < 32; ++d)
      acc += bq[h * 32 + d] * key[(r * 8 + h) * 32 + d];
    bqk[i] = acc * 0.17677669529663687f;
  }
}

// ---------------------------------------------------------------------------
// K1: fused RMSNorm: x1 = rms(x)*w1 ; z1 = rms(sg*x1 + sd*z)*w2. bf16 out.
// One wave per token (256 elems = float4/lane).
// ---------------------------------------------------------------------------
__global__ __launch_bounds__(256) void k_norm(
    const float* __restrict__ x, const float* __restrict__ z,
    const float* __restrict__ nw1, const float* __restrict__ nw2,
    const float* __restrict__ gamma, const float* __restrict__ delta,
    short* __restrict__ x1bp, short* __restrict__ z1bp)
{
  int tok = blockIdx.x * 4 + (threadIdx.x >> 6);
  int lane = threadIdx.x & 63;
  size_t rbase = (size_t)tok * DD;
  float4 xv = ((const float4*)(x + rbase))[lane];
  float ss = xv.x*xv.x + xv.y*xv.y + xv.z*xv.z + xv.w*xv.w;
  #pragma unroll
  for (int mm = 1; mm < 64; mm <<= 1) ss += __shfl_xor(ss, mm);
  float inv = rsqrtf(ss * 0.00390625f + 1e-6f);
  float4 wv = ((const float4*)nw1)[lane];
  float xa = xv.x * inv * wv.x, xb = xv.y * inv * wv.y,
        xc = xv.z * inv * wv.z, xd = xv.w * inv * wv.w;
  bf16x4 xo = { f2b(xa), f2b(xb), f2b(xc), f2b(xd) };
  ((bf16x4*)(x1bp + rbase))[lane] = xo;
  float sg = sigf(gamma[0]), sd = sigf(delta[0]);
  float4 zv = ((const float4*)(z + rbase))[lane];
  float t0 = sg*xa + sd*zv.x, t1 = sg*xb + sd*zv.y,
        t2 = sg*xc + sd*zv.z, t3 = sg*xd + sd*zv.w;
  float s2 = t0*t0 + t1*t1 + t2*t2 + t3*t3;
  #pragma unroll
  for (int mm = 1; mm < 64; mm <<= 1) s2 += __shfl_xor(s2, mm);
  float inv2 = rsqrtf(s2 * 0.00390625f + 1e-6f);
  float4 w2v = ((const float4*)nw2)[lane];
  bf16x4 zo = { f2b(t0*inv2*w2v.x), f2b(t1*inv2*w2v.y),
                f2b(t2*inv2*w2v.z), f2b(t3*inv2*w2v.w) };
  ((bf16x4*)(z1bp + rbase))[lane] = zo;
}

// ---------------------------------------------------------------------------
// K2/K3: C_bf16[MT,256] = A_bf16[MT,256] @ Bt^T + bias. Bt is [256][256] in
// [n][k] layout. 64x64 tile, 4 waves each 32x32 (2x2 MFMA tiles).
// ---------------------------------------------------------------------------
__global__ __launch_bounds__(256) void k_gemm256(
    const short* __restrict__ A, const short* __restrict__ Bt,
    const float* __restrict__ bias, short* __restrict__ C)
{
  __shared__ __align__(16) short As[64 * 40];  // +8 pad: 2-way-at-worst banks
  __shared__ __align__(16) short Bs[64 * 40];
  int row0 = blockIdx.x * 64, col0 = blockIdx.y * 64;
  int tid = threadIdx.x, lane = tid & 63, w = tid >> 6;
  int mh = (w & 1) * 32, nh = (w >> 1) * 32;
  int l15 = lane & 15, ko = (lane >> 4) * 8;
  int lrow = tid >> 2, lch = (tid & 3) * 8;
  f32x4 acc[2][2] = {};
  for (int k0 = 0; k0 < 256; k0 += 32) {
    *(bf16x8*)&As[lrow * 40 + lch] = *(const bf16x8*)&A[(row0 + lrow) * 256 + k0 + lch];
    *(bf16x8*)&Bs[lrow * 40 + lch] = *(const bf16x8*)&Bt[(col0 + lrow) * 256 + k0 + lch];
    __syncthreads();
    bf16x8 af[2], bfr[2];
    #pragma unroll
    for (int t = 0; t < 2; ++t) {
      af[t]  = *(const bf16x8*)&As[(mh + t * 16 + l15) * 40 + ko];
      bfr[t] = *(const bf16x8*)&Bs[(nh + t * 16 + l15) * 40 + ko];
    }
    #pragma unroll
    for (int tm = 0; tm < 2; ++tm)
      #pragma unroll
      for (int tn = 0; tn < 2; ++tn)
        acc[tm][tn] = mfma16(af[tm], bfr[tn], acc[tm][tn]);
    __syncthreads();
  }
  #pragma unroll
  for (int tm = 0; tm < 2; ++tm)
    #pragma unroll
    for (int tn = 0; tn < 2; ++tn) {
      int n = col0 + nh + tn * 16 + l15;
      float bv = bias[n];
      #pragma unroll
      for (int r = 0; r < 4; ++r) {
        int m = row0 + mh + tm * 16 + (lane >> 4) * 4 + r;
        C[m * 256 + n] = f2b(acc[tm][tn][r] + bv);
      }
    }
}

// ---------------------------------------------------------------------------
// K4: fused SwiGLU FFN. Per block: 64 rows x full 256 out cols.
// A (64x256) staged once in LDS; loop 8 chunks of E (128 wide):
//   stage1: h = silu(A@W1c+b1)*(A@W2c+b2)  -> bf16 in LDS
//   stage2: oacc += h @ W3c
// out = sig(alpha) * (oacc + b3), fp32 (overwrites poisoned d_out).
// ---------------------------------------------------------------------------
__global__ __launch_bounds__(256) void k_ffn(
    const short* __restrict__ x1bp,
    const short* __restrict__ W1t, const short* __restrict__ W2t,
    const short* __restrict__ W3t,
    const float* __restrict__ b1, const float* __restrict__ b2,
    const float* __restrict__ b3, const float* __restrict__ alpha,
    float* __restrict__ out)
{
  __shared__ __align__(16) short As[64 * 264];  // 64 x (256+8)
  __shared__ __align__(16) short Hs[64 * 136];  // 64 x (128+8)
  int row0 = blockIdx.x * 64;
  int tid = threadIdx.x, lane = tid & 63, w = tid >> 6;
  int l15 = lane & 15, ko = (lane >> 4) * 8;
  #pragma unroll
  for (int it = 0; it < 8; ++it) {
    int idx = it * 256 + tid;
    int rw = idx >> 5, ch = (idx & 31) * 8;
    *(bf16x8*)&As[rw * 264 + ch] = *(const bf16x8*)&x1bp[(row0 + rw) * 256 + ch];
  }
  __syncthreads();
  f32x4 oacc[4][4] = {};
  for (int ec = 0; ec < 8; ++ec) {
    int e0 = ec * 128;
    f32x4 h1[4][2] = {}, h2[4][2] = {};
    #pragma unroll
    for (int kk = 0; kk < 8; ++kk) {
      int k0 = kk * 32;
      bf16x8 af[4];
      #pragma unroll
      for (int tm = 0; tm < 4; ++tm)
        af[tm] = *(const bf16x8*)&As[(tm * 16 + l15) * 264 + k0 + ko];
      #pragma unroll
      for (int tn = 0; tn < 2; ++tn) {
        int e = e0 + w * 32 + tn * 16 + l15;
        bf16x8 w1f = *(const bf16x8*)&W1t[e * 256 + k0 + ko];
        bf16x8 w2f = *(const bf16x8*)&W2t[e * 256 + k0 + ko];
        #pragma unroll
        for (int tm = 0; tm < 4; ++tm) {
          h1[tm][tn] = mfma16(af[tm], w1f, h1[tm][tn]);
          h2[tm][tn] = mfma16(af[tm], w2f, h2[tm][tn]);
        }
      }
    }
    #pragma unroll
    for (int tn = 0; tn < 2; ++tn) {
      int e = e0 + w * 32 + tn * 16 + l15;
      float c1 = b1[e], c2 = b2[e];
      int eloc = w * 32 + tn * 16 + l15;
      #pragma unroll
      for (int tm = 0; tm < 4; ++tm)
        #pragma unroll
        for (int r = 0; r < 4; ++r) {
          float v1 = h1[tm][tn][r] + c1;
          float v2 = h2[tm][tn][r] + c2;
          float hv = v1 * sigf(v1) * v2;  // silu(v1) * v2
          int m = tm * 16 + (lane >> 4) * 4 + r;
          Hs[m * 136 + eloc] = f2b(hv);
        }
    }
    __syncthreads();
    #pragma unroll
    for (int kk = 0; kk < 4; ++kk) {
      int k0 = kk * 32;
      bf16x8 hf[4];
      #pragma unroll
      for (int tm = 0; tm < 4; ++tm)
        hf[tm] = *(const bf16x8*)&Hs[(tm * 16 + l15) * 136 + k0 + ko];
      #pragma unroll
      for (int tn = 0; tn < 4; ++tn) {
        int n = w * 64 + tn * 16 + l15;
        bf16x8 w3f = *(const bf16x8*)&W3t[n * 1024 + e0 + k0 + ko];
        #pragma unroll
        for (int tm = 0; tm < 4; ++tm)
          oacc[tm][tn] = mfma16(hf[tm], w3f, oacc[tm][tn]);
      }
    }
    __syncthreads();
  }
  float sa = sigf(alpha[0]);
  #pragma unroll
  for (int tn = 0; tn < 4; ++tn) {
    int n = w * 64 + tn * 16 + l15;
    float bb = b3[n];
    #pragma unroll
    for (int tm = 0; tm < 4; ++tm)
      #pragma unroll
      for (int r = 0; r < 4; ++r) {
        int m = row0 + tm * 16 + (lane >> 4) * 4 + r;
        out[m * 256 + n] = sa * (oacc[tm][tn][r] + bb);
      }
  }
}

// ---------------------------------------------------------------------------
// K5: attention pass 1. One block per (b,t,h). Row softmax P1 over r,
// v1[r][d] = sum_n P1[n][r]*xv[n][d], plus online column (over n) max/sum.
// Threads: r = tid&31, nl = tid>>5 (8 n-rows per iter, 125 iters).
// ---------------------------------------------------------------------------
__global__ __launch_bounds__(256) void k_attn1(
    const short* __restrict__ attnb, const short* __restrict__ xvb,
    float* __restrict__ v1buf, float* __restrict__ colmax, float* __restrict__ colsum)
{
  __shared__ float xr[8][32];
  __shared__ float red[8][32][32];
  __shared__ float mred[8][32], sred[8][32];
  int gid = blockIdx.x;            // bt*8 + h
  int bt = gid >> 3, h = gid & 7;
  int tid = threadIdx.x, r = tid & 31, nl = tid >> 5;
  int base = bt * NSEQ;
  float accd[32];
  #pragma unroll
  for (int d = 0; d < 32; ++d) accd[d] = 0.f;
  float mrun = -1e30f, srun = 0.f;
  for (int it = 0; it < 125; ++it) {
    int tok = base + it * 8 + nl;
    float a = b2f(attnb[tok * 256 + h * 32 + r]);
    float rmax = a;
    #pragma unroll
    for (int mm = 16; mm > 0; mm >>= 1) rmax = fmaxf(rmax, __shfl_xor(rmax, mm));
    float ea = __expf(a - rmax);
    float rsum = ea;
    #pragma unroll
    for (int mm = 16; mm > 0; mm >>= 1) rsum += __shfl_xor(rsum, mm);
    float p1 = ea / rsum;
    float nm = fmaxf(mrun, a);                       // online col stats
    srun = srun * __expf(mrun - nm) + __expf(a - nm);
    mrun = nm;
    xr[nl][r] = b2f(xvb[tok * 256 + h * 32 + r]);
    __syncthreads();
    #pragma unroll
    for (int d = 0; d < 32; ++d) accd[d] += p1 * xr[nl][d];
    __syncthreads();
  }
  #pragma unroll
  for (int d = 0; d < 32; ++d) red[nl][r][d] = accd[d];
  mred[nl][r] = mrun; sred[nl][r] = srun;
  __syncthreads();
  for (int s = 4; s > 0; s >>= 1) {
    if (nl < s)
      #pragma unroll
      for (int d = 0; d < 32; ++d) red[nl][r][d] += red[nl + s][r][d];
    __syncthreads();
  }
  if (nl == 0) {
    for (int d = 0; d < 32; ++d) v1buf[gid * 1024 + r * 32 + d] = red[0][r][d];
    float Mv = -1e30f;
    for (int j = 0; j < 8; ++j) Mv = fmaxf(Mv, mred[j][r]);
    float Sv = 0.f;
    for (int j = 0; j < 8; ++j) Sv += sred[j][r] * __expf(mred[j][r] - Mv);
    colmax[gid * 32 + r] = Mv;
    colsum[gid * 32 + r] = Sv;
  }
}

// ---------------------------------------------------------------------------
// K6: attention pass 2 + final blend.
// v2[n][d] = sum_r P2[n][r]*v1[r][d]; out += sig(beta)*(sig(mha_a)*xv + sig(mha_b)*v2)
// One block per (bt, chunk-of-100-tokens); thread = output column c = h*32+d.
// ---------------------------------------------------------------------------
__global__ __launch_bounds__(256) void k_attn2(
    const short* __restrict__ attnb, const short* __restrict__ xvb,
    const float* __restrict__ v1buf, const float* __restrict__ colmax,
    const float* __restrict__ colsum, const float* __restrict__ mha_alpha,
    const float* __restrict__ mha_beta, const float* __restrict__ beta,
    float* __restrict__ out)
{
  __shared__ float v1s[8 * 1024];
  __shared__ float cms[256], css[256], p2s[256];
  __shared__ float sas[8], sbs[8];
  int bt = blockIdx.x, chunk = blockIdx.y;
  int tid = threadIdx.x;
  for (int j = 0; j < 32; ++j) v1s[tid * 32 + j] = v1buf[bt * 8192 + tid * 32 + j];
  cms[tid] = colmax[bt * 256 + tid];
  css[tid] = colsum[bt * 256 + tid];
  if (tid < 8) { sas[tid] = sigf(mha_alpha[tid]); sbs[tid] = sigf(mha_beta[tid]); }
  __syncthreads();
  float sbeta = sigf(beta[0]);
  int h = tid >> 5, d = tid & 31;
  for (int tl = 0; tl < 100; ++tl) {
    int tok = bt * NSEQ + chunk * 100 + tl;
    float a = b2f(attnb[tok * 256 + tid]);
    p2s[tid] = __expf(a - cms[tid]) / css[tid];
    float xvv = b2f(xvb[tok * 256 + tid]);
    __syncthreads();
    float v2 = 0.f;
    #pragma unroll
    for (int rr = 0; rr < 32; ++rr)
      v2 += p2s[h * 32 + rr] * v1s[h * 1024 + rr * 32 + d];
    out[tok * 256 + tid] += sbeta * (sas[h] * xvv + sbs[h] * v2);
    __syncthreads();
  }
}

// ---------------------------------------------------------------------------
extern "C" void kernel_launch(void* const* d_in, const int* in_sizes, int n_in,
                              void* d_out, int out_size, void* d_ws, size_t ws_size,
                              hipStream_t stream) {
  const float* x        = (const float*)d_in[0];
  const float* z        = (const float*)d_in[1];
  const float* norm1_w  = (const float*)d_in[2];
  const float* norm2_w  = (const float*)d_in[3];
  const float* alpha    = (const float*)d_in[4];
  const float* beta     = (const float*)d_in[5];
  const float* gamma    = (const float*)d_in[6];
  const float* delta    = (const float*)d_in[7];
  const float* Wq       = (const float*)d_in[8];
  const float* bq       = (const float*)d_in[9];
  const float* key      = (const float*)d_in[10];
  const float* Wv       = (const float*)d_in[11];
  const float* bv       = (const float*)d_in[12];
  const float* mha_a    = (const float*)d_in[13];
  const float* mha_b    = (const float*)d_in[14];
  const float* W1       = (const float*)d_in[15];
  const float* b1       = (const float*)d_in[16];
  const float* W2       = (const float*)d_in[17];
  const float* b2       = (const float*)d_in[18];
  const float* W3       = (const float*)d_in[19];
  const float* b3       = (const float*)d_in[20];
  float* out = (float*)d_out;
  char* ws = (char*)d_ws;

  short* x1b   = (short*)(ws);
  short* z1b   = (short*)(ws + 49152000);
  short* xvb   = (short*)(ws + 98304000);
  short* attnb = (short*)(ws + 147456000);
  short* W1t   = (short*)(ws + 196608000);
  short* W2t   = (short*)(ws + 197132288);
  short* W3t   = (short*)(ws + 197656576);
  short* Wvt   = (short*)(ws + 198180864);
  short* Wqkt  = (short*)(ws + 198311936);
  float* bqk   = (float*)(ws + 198443008);
  float* v1buf = (float*)(ws + 198444032);
  float* colmax= (float*)(ws + 201589760);
  float* colsum= (float*)(ws + 201688064);

  hipLaunchKernelGGL(k_prep, dim3(1024), dim3(256), 0, stream,
                     Wq, bq, key, Wv, W1, W2, W3, W1t, W2t, W3t, Wvt, Wqkt, bqk);
  hipLaunchKernelGGL(k_norm, dim3(MT / 4), dim3(256), 0, stream,
                     x, z, norm1_w, norm2_w, gamma, delta, x1b, z1b);
  hipLaunchKernelGGL(k_gemm256, dim3(MT / 64, 4), dim3(256), 0, stream,
                     z1b, Wqkt, bqk, attnb);
  hipLaunchKernelGGL(k_gemm256, dim3(MT / 64, 4), dim3(256), 0, stream,
                     x1b, Wvt, bv, xvb);
  hipLaunchKernelGGL(k_ffn, dim3(MT / 64), dim3(256), 0, stream,
                     x1b, W1t, W2t, W3t, b1, b2, b3, alpha, out);
  hipLaunchKernelGGL(k_attn1, dim3(NBT * 8), dim3(256), 0, stream,
                     attnb, xvb, v1buf, colmax, colsum);
  hipLaunchKernelGGL(k_attn2, dim3(NBT, 10), dim3(256), 0, stream,
                     attnb, xvb, v1buf, colmax, colsum, mha_a, mha_b, beta, out);
}